// Round 1
// baseline (329.021 us; speedup 1.0000x reference)
//
#include <hip/hip_runtime.h>

#define BATCH 16
#define HW (768 * 768)     // 589824 pixels per batch-image
#define NIDS 128
#define GROUPS (HW / 4)    // 147456 int4/float4 groups per batch

// ---------------------------------------------------------------------------
// ws layout:
//   [0,      8192)  : unsigned int counts[16][128]
//   [8192,  16384)  : float inv_norm[16][128]
//   [16384, 16512)  : float sums[32]  (sums[b] = sin, sums[16+b] = cos)
// ---------------------------------------------------------------------------

__global__ __launch_bounds__(256) void hist_kernel(const int* __restrict__ inst,
                                                   unsigned int* __restrict__ counts) {
    __shared__ unsigned int lhist[NIDS];
    const int b = blockIdx.y;
    for (int i = threadIdx.x; i < NIDS; i += blockDim.x) lhist[i] = 0u;
    __syncthreads();

    const int4* src = (const int4*)(inst + (size_t)b * HW);
    for (int g = blockIdx.x * blockDim.x + threadIdx.x; g < GROUPS;
         g += gridDim.x * blockDim.x) {
        int4 v = src[g];
        atomicAdd(&lhist[v.x & 127], 1u);
        atomicAdd(&lhist[v.y & 127], 1u);
        atomicAdd(&lhist[v.z & 127], 1u);
        atomicAdd(&lhist[v.w & 127], 1u);
    }
    __syncthreads();
    for (int i = threadIdx.x; i < NIDS; i += blockDim.x)
        if (lhist[i]) atomicAdd(&counts[b * NIDS + i], lhist[i]);
}

__global__ __launch_bounds__(256) void norm_kernel(const unsigned int* __restrict__ counts,
                                                   float* __restrict__ inv_norm,
                                                   float* __restrict__ sums) {
    // single block of 256 threads
    unsigned int ninst = 0u, nbg = 0u;
    for (int i = threadIdx.x; i < BATCH * NIDS; i += blockDim.x) {
        const unsigned int c = counts[i];
        if ((i & 127) == 0) nbg += c;
        else ninst += (c > 0u) ? 1u : 0u;
    }
    for (int off = 32; off; off >>= 1) {
        ninst += __shfl_down(ninst, off, 64);
        nbg   += __shfl_down(nbg,   off, 64);
    }
    __shared__ unsigned int s_ninst[4], s_nbg[4];
    __shared__ float s_f[2];
    const int wid = threadIdx.x >> 6, lane = threadIdx.x & 63;
    if (lane == 0) { s_ninst[wid] = ninst; s_nbg[wid] = nbg; }
    __syncthreads();
    if (threadIdx.x == 0) {
        unsigned int a = 0u, c = 0u;
        for (int i = 0; i < 4; ++i) { a += s_ninst[i]; c += s_nbg[i]; }
        s_f[0] = (float)a;   // num_instances
        s_f[1] = (float)c;   // num_bg_pixels
    }
    __syncthreads();
    const float num_instances = s_f[0];
    const float num_bg = s_f[1];
    for (int i = threadIdx.x; i < BATCH * NIDS; i += blockDim.x) {
        const float c = (float)counts[i];
        // match reference eval order: (max(c,1)*num_instances)*2
        const float norm = ((i & 127) == 0) ? (num_bg * 2.0f)
                                            : (fmaxf(c, 1.0f) * num_instances * 2.0f);
        inv_norm[i] = 1.0f / norm;
    }
    if (threadIdx.x < 32) sums[threadIdx.x] = 0.0f;
}

__global__ __launch_bounds__(256) void loss_kernel(const int* __restrict__ inst,
                                                   const float* __restrict__ pred,
                                                   const float* __restrict__ gt,
                                                   const float* __restrict__ inv_norm,
                                                   float* __restrict__ sums) {
    __shared__ float tbl[NIDS];
    const int b = blockIdx.y;
    for (int i = threadIdx.x; i < NIDS; i += blockDim.x) tbl[i] = inv_norm[b * NIDS + i];
    __syncthreads();

    const int4*   ip = (const int4*)  (inst + (size_t)b * HW);
    const float4* ps = (const float4*)(pred + (size_t)b * 2 * HW);
    const float4* pc = (const float4*)(pred + (size_t)b * 2 * HW + HW);
    const float4* gs = (const float4*)(gt   + (size_t)b * 5 * HW + 2 * (size_t)HW);
    const float4* gc = (const float4*)(gt   + (size_t)b * 5 * HW + 3 * (size_t)HW);

    float acc_s = 0.0f, acc_c = 0.0f;
    for (int g = blockIdx.x * blockDim.x + threadIdx.x; g < GROUPS;
         g += gridDim.x * blockDim.x) {
        const int4   v = ip[g];
        const float4 a = ps[g];
        const float4 p = pc[g];
        const float4 c = gs[g];
        const float4 d = gc[g];
        const float w0 = tbl[v.x & 127];
        const float w1 = tbl[v.y & 127];
        const float w2 = tbl[v.z & 127];
        const float w3 = tbl[v.w & 127];
        acc_s += w0 * fabsf(a.x - c.x) + w1 * fabsf(a.y - c.y) +
                 w2 * fabsf(a.z - c.z) + w3 * fabsf(a.w - c.w);
        acc_c += w0 * fabsf(p.x - d.x) + w1 * fabsf(p.y - d.y) +
                 w2 * fabsf(p.z - d.z) + w3 * fabsf(p.w - d.w);
    }

    for (int off = 32; off; off >>= 1) {
        acc_s += __shfl_down(acc_s, off, 64);
        acc_c += __shfl_down(acc_c, off, 64);
    }
    __shared__ float s_s[4], s_c[4];
    const int wid = threadIdx.x >> 6, lane = threadIdx.x & 63;
    if (lane == 0) { s_s[wid] = acc_s; s_c[wid] = acc_c; }
    __syncthreads();
    if (threadIdx.x == 0) {
        float ts = 0.0f, tc = 0.0f;
        for (int i = 0; i < 4; ++i) { ts += s_s[i]; tc += s_c[i]; }
        atomicAdd(&sums[b], ts);
        atomicAdd(&sums[BATCH + b], tc);
    }
}

__global__ void fin_kernel(const float* __restrict__ sums, float* __restrict__ out) {
    const int b = threadIdx.x;
    if (b < BATCH) {
        const float s = sums[b];
        const float c = sums[BATCH + b];
        const float tot = s + c;
        out[b]      = tot;   // loss
        out[16 + b] = tot;   // loss_direction_total
        out[32 + b] = 0.0f;  // loss_centers
        out[48 + b] = s;     // loss_sin
        out[64 + b] = c;     // loss_cos
    }
}

extern "C" void kernel_launch(void* const* d_in, const int* in_sizes, int n_in,
                              void* d_out, int out_size, void* d_ws, size_t ws_size,
                              hipStream_t stream) {
    const float* prediction = (const float*)d_in[0];
    const int*   instances  = (const int*)d_in[1];
    // d_in[2] = labels: unused (W_BG == W_FG == 1.0 makes base weight == 1)
    const float* centerdir  = (const float*)d_in[3];
    float* out = (float*)d_out;

    unsigned int* counts  = (unsigned int*)d_ws;
    float* inv_norm       = (float*)((char*)d_ws + 8192);
    float* sums           = (float*)((char*)d_ws + 16384);

    hipMemsetAsync(counts, 0, BATCH * NIDS * sizeof(unsigned int), stream);

    hist_kernel<<<dim3(72, BATCH), 256, 0, stream>>>(instances, counts);
    norm_kernel<<<1, 256, 0, stream>>>(counts, inv_norm, sums);
    loss_kernel<<<dim3(144, BATCH), 256, 0, stream>>>(instances, prediction, centerdir,
                                                      inv_norm, sums);
    fin_kernel<<<1, 64, 0, stream>>>(sums, out);
}